// Round 1
// baseline (2688.596 us; speedup 1.0000x reference)
//
#include <hip/hip_runtime.h>

// Segment-sum: out[v, :] = sum over rows n with X_node[n]==v of H[n, :]
// H: [N=1.6M, 128] f32, X_node: [N] i32, out: [V=50000, 128] f32.

#define D 128
#define F4_PER_ROW (D / 4)

__global__ void zero_out_kernel(float4* __restrict__ out, int n4) {
    int i = blockIdx.x * blockDim.x + threadIdx.x;
    int stride = gridDim.x * blockDim.x;
    for (; i < n4; i += stride) {
        out[i] = make_float4(0.f, 0.f, 0.f, 0.f);
    }
}

__global__ void scatter_add_kernel(const float4* __restrict__ H4,
                                   const int* __restrict__ idx,
                                   float* __restrict__ out,
                                   int n_rows) {
    // One thread per float4 of H. Consecutive threads -> consecutive 16B
    // within a row (coalesced). 32 float4 per row; the 32 threads of a row
    // share the same idx[n] load (L1 broadcast).
    const long total = (long)n_rows * F4_PER_ROW;
    long i = (long)blockIdx.x * blockDim.x + threadIdx.x;
    const long stride = (long)gridDim.x * blockDim.x;
    for (; i < total; i += stride) {
        const int n  = (int)(i >> 5);   // / F4_PER_ROW
        const int d4 = (int)(i & 31);   // % F4_PER_ROW
        const float4 h = H4[i];
        const int v = idx[n];
        float* o = out + (long)v * D + d4 * 4;
        atomicAdd(o + 0, h.x);
        atomicAdd(o + 1, h.y);
        atomicAdd(o + 2, h.z);
        atomicAdd(o + 3, h.w);
    }
}

extern "C" void kernel_launch(void* const* d_in, const int* in_sizes, int n_in,
                              void* d_out, int out_size, void* d_ws, size_t ws_size,
                              hipStream_t stream) {
    const float* H      = (const float*)d_in[0];
    const int*   X_node = (const int*)d_in[1];
    // d_in[2] is V (scalar) — output size is out_size = V*D anyway.

    const int n_rows = in_sizes[1];          // N = 1,600,000
    float* out = (float*)d_out;

    // 1) zero the output (harness poisons d_out; we must produce exact sums).
    {
        const int n4 = out_size / 4;         // 6.4M floats -> 1.6M float4
        const int block = 256;
        const int grid = 2048;
        zero_out_kernel<<<grid, block, 0, stream>>>((float4*)out, n4);
    }

    // 2) scatter-add all rows.
    {
        const int block = 256;
        const int grid = 2048;               // grid-stride; ~98 float4/thread
        scatter_add_kernel<<<grid, block, 0, stream>>>(
            (const float4*)H, X_node, out, n_rows);
    }
}

// Round 2
// 379.989 us; speedup vs baseline: 7.0755x; 7.0755x over previous
//
#include <hip/hip_runtime.h>

// Segment-sum via counting sort + gather reduce (no float atomics).
// H: [N=1.6M, 128] f32, X_node: [N] i32, out: [V=50000, 128] f32.
//
// Phases:
//  1. hist[v]   = count of rows with X_node==v           (int atomics)
//  2. offsets   = exclusive scan(hist), offsets[V] = N   (3 small kernels)
//  3. order[]   = row indices grouped by bucket          (int atomics)
//  4. per-bucket wave gathers rows of H, sums, writes out once (no atomics)

#define D 128
#define BLOCK 256
#define CHUNK 1024        // hist elements per scan block
#define K 4               // CHUNK / BLOCK

// ---------------- phase 1: histogram ----------------
__global__ void hist_kernel(const int* __restrict__ idx, int* __restrict__ hist, int n) {
    int i = blockIdx.x * blockDim.x + threadIdx.x;
    int stride = gridDim.x * blockDim.x;
    for (; i < n; i += stride) atomicAdd(&hist[idx[i]], 1);
}

// ---------------- phase 2: scan ----------------
__global__ void chunk_sum_kernel(const int* __restrict__ hist, int* __restrict__ bsum, int V) {
    __shared__ int lds[BLOCK];
    const int b = blockIdx.x, t = threadIdx.x;
    const int base = b * CHUNK + t * K;
    int s = 0;
#pragma unroll
    for (int i = 0; i < K; ++i) { int g = base + i; if (g < V) s += hist[g]; }
    lds[t] = s; __syncthreads();
    for (int off = BLOCK / 2; off > 0; off >>= 1) {
        if (t < off) lds[t] += lds[t + off];
        __syncthreads();
    }
    if (t == 0) bsum[b] = lds[0];
}

__global__ void scan_bsum_kernel(int* bsum, int nb) {
    // single block of 64 threads; nb <= 64
    __shared__ int lds[64];
    const int t = threadIdx.x;
    const int v = (t < nb) ? bsum[t] : 0;
    lds[t] = v; __syncthreads();
    for (int off = 1; off < 64; off <<= 1) {
        int add = (t >= off) ? lds[t - off] : 0;
        __syncthreads();
        lds[t] += add;
        __syncthreads();
    }
    if (t < nb) bsum[t] = lds[t] - v;   // exclusive
}

__global__ void chunk_scan_kernel(const int* __restrict__ hist, const int* __restrict__ bsum,
                                  int* __restrict__ offsets, int* __restrict__ cursor,
                                  int V) {
    __shared__ int lds[BLOCK];
    const int b = blockIdx.x, t = threadIdx.x;
    const int base = b * CHUNK + t * K;
    int v[K]; int s = 0;
#pragma unroll
    for (int i = 0; i < K; ++i) { int g = base + i; v[i] = (g < V) ? hist[g] : 0; s += v[i]; }
    lds[t] = s; __syncthreads();
    for (int off = 1; off < BLOCK; off <<= 1) {
        int add = (t >= off) ? lds[t - off] : 0;
        __syncthreads();
        lds[t] += add;
        __syncthreads();
    }
    int run = bsum[b] + lds[t] - s;   // global exclusive prefix for this thread
#pragma unroll
    for (int i = 0; i < K; ++i) {
        int g = base + i;
        if (g < V) {
            offsets[g] = run;
            cursor[g]  = run;
            run += v[i];
            if (g == V - 1) offsets[V] = run;   // == N
        }
    }
}

// ---------------- phase 3: scatter indices ----------------
__global__ void scatter_kernel(const int* __restrict__ idx, int* __restrict__ cursor,
                               int* __restrict__ order, int n) {
    int i = blockIdx.x * blockDim.x + threadIdx.x;
    int stride = gridDim.x * blockDim.x;
    for (; i < n; i += stride) {
        int v = idx[i];
        int p = atomicAdd(&cursor[v], 1);
        order[p] = i;
    }
}

// ---------------- phase 4: gather + reduce ----------------
__global__ void __launch_bounds__(BLOCK) reduce_kernel(const float2* __restrict__ H2,
                                                       const int* __restrict__ order,
                                                       const int* __restrict__ offsets,
                                                       float2* __restrict__ out, int V) {
    const int gid  = blockIdx.x * blockDim.x + threadIdx.x;
    const int wave = gid >> 6;      // one wavefront (64 lanes) per bucket
    const int lane = gid & 63;      // lane owns float2 at column 2*lane
    if (wave >= V) return;
    const int start = offsets[wave];
    const int end   = offsets[wave + 1];
    float ax = 0.f, ay = 0.f;
    int r = start;
    for (; r + 4 <= end; r += 4) {          // 4 independent row loads in flight
        const int n0 = order[r + 0], n1 = order[r + 1];
        const int n2 = order[r + 2], n3 = order[r + 3];
        const float2 a = H2[(size_t)n0 * 64 + lane];
        const float2 b = H2[(size_t)n1 * 64 + lane];
        const float2 c = H2[(size_t)n2 * 64 + lane];
        const float2 d = H2[(size_t)n3 * 64 + lane];
        ax += a.x + b.x + c.x + d.x;
        ay += a.y + b.y + c.y + d.y;
    }
    for (; r < end; ++r) {
        const float2 a = H2[(size_t)order[r] * 64 + lane];
        ax += a.x; ay += a.y;
    }
    out[(size_t)wave * 64 + lane] = make_float2(ax, ay);
}

// ---------------- fallback (round-1 atomic path, if ws too small) ----------------
__global__ void zero_out_kernel(float4* __restrict__ out, int n4) {
    int i = blockIdx.x * blockDim.x + threadIdx.x;
    int stride = gridDim.x * blockDim.x;
    for (; i < n4; i += stride) out[i] = make_float4(0.f, 0.f, 0.f, 0.f);
}

__global__ void scatter_add_kernel(const float4* __restrict__ H4, const int* __restrict__ idx,
                                   float* __restrict__ out, int n_rows) {
    const long total = (long)n_rows * (D / 4);
    long i = (long)blockIdx.x * blockDim.x + threadIdx.x;
    const long stride = (long)gridDim.x * blockDim.x;
    for (; i < total; i += stride) {
        const int n  = (int)(i >> 5);
        const int d4 = (int)(i & 31);
        const float4 h = H4[i];
        const int v = idx[n];
        float* o = out + (long)v * D + d4 * 4;
        atomicAdd(o + 0, h.x); atomicAdd(o + 1, h.y);
        atomicAdd(o + 2, h.z); atomicAdd(o + 3, h.w);
    }
}

extern "C" void kernel_launch(void* const* d_in, const int* in_sizes, int n_in,
                              void* d_out, int out_size, void* d_ws, size_t ws_size,
                              hipStream_t stream) {
    const float* H      = (const float*)d_in[0];
    const int*   X_node = (const int*)d_in[1];
    const int N = in_sizes[1];
    const int V = out_size / D;
    float* out = (float*)d_out;

    const int NB = (V + CHUNK - 1) / CHUNK;   // 49 for V=50000
    const size_t need = ((size_t)V + (size_t)(V + 1) + (size_t)V + (size_t)N + (size_t)NB)
                        * sizeof(int);

    if (ws_size < need || NB > 64) {
        // fallback: pure atomic scatter-add (round-1 path)
        zero_out_kernel<<<2048, BLOCK, 0, stream>>>((float4*)out, out_size / 4);
        scatter_add_kernel<<<2048, BLOCK, 0, stream>>>((const float4*)H, X_node, out, N);
        return;
    }

    int* hist    = (int*)d_ws;        // V
    int* offsets = hist + V;          // V+1
    int* cursor  = offsets + V + 1;   // V
    int* order   = cursor + V;        // N
    int* bsum    = order + N;         // NB

    hipMemsetAsync(hist, 0, (size_t)V * sizeof(int), stream);
    hist_kernel<<<2048, BLOCK, 0, stream>>>(X_node, hist, N);
    chunk_sum_kernel<<<NB, BLOCK, 0, stream>>>(hist, bsum, V);
    scan_bsum_kernel<<<1, 64, 0, stream>>>(bsum, NB);
    chunk_scan_kernel<<<NB, BLOCK, 0, stream>>>(hist, bsum, offsets, cursor, V);
    scatter_kernel<<<2048, BLOCK, 0, stream>>>(X_node, cursor, order, N);
    reduce_kernel<<<(V * 64 + BLOCK - 1) / BLOCK, BLOCK, 0, stream>>>(
        (const float2*)H, order, offsets, (float2*)out, V);
}